// Round 6
// baseline (190.026 us; speedup 1.0000x reference)
//
#include <hip/hip_runtime.h>
#include <math.h>

// Problem constants (from reference)
constexpr int B_ = 8;
constexpr int N_ = 8192;
constexpr int K_ = 48;
constexpr int NFREQ = 8;    // NUM_POS/2
constexpr int NEDGE = 16;
constexpr int FANIN = 23;   // NUM_POS + 7
constexpr float EPSF = 1e-12f;
constexpr int DRANGE = 2 * N_ - 1;  // 16383 possible d = j-n values, offset N_-1

// ---------------- helpers ----------------
struct F3 { float x, y, z; };
__device__ inline F3 f3(float a, float b, float c) { F3 r{a,b,c}; return r; }
__device__ inline F3 sub3(F3 a, F3 b) { return f3(a.x-b.x, a.y-b.y, a.z-b.z); }
__device__ inline F3 cross3(F3 a, F3 b) {
    return f3(a.y*b.z - a.z*b.y, a.z*b.x - a.x*b.z, a.x*b.y - a.y*b.x);
}
__device__ inline F3 norm3(F3 a) {
    float n = sqrtf(a.x*a.x + a.y*a.y + a.z*a.z);
    float inv = 1.0f / fmaxf(n, EPSF);
    return f3(a.x*inv, a.y*inv, a.z*inv);
}
__device__ inline float signf0(float x) {
    return (x > 0.0f) ? 1.0f : ((x < 0.0f) ? -1.0f : 0.0f);
}
__device__ inline unsigned int bf16rne(float x) {
    unsigned int u = __float_as_uint(x);
    return (u + 0x7fffu + ((u >> 16) & 1u)) >> 16;
}
// unpack 8 bf16 (one uint4) -> 8 floats
__device__ inline void unpack8(uint4 v, float* f) {
    f[0] = __uint_as_float(v.x << 16); f[1] = __uint_as_float(v.x & 0xffff0000u);
    f[2] = __uint_as_float(v.y << 16); f[3] = __uint_as_float(v.y & 0xffff0000u);
    f[4] = __uint_as_float(v.z << 16); f[5] = __uint_as_float(v.z & 0xffff0000u);
    f[6] = __uint_as_float(v.w << 16); f[7] = __uint_as_float(v.w & 0xffff0000u);
}

// ---------------- kernel 1: positional-encoding table (bf16, 32B rows) ----------------
__global__ void build_table(const float* __restrict__ tfrq, const float* __restrict__ ts,
                            const float* __restrict__ W, const float* __restrict__ bias,
                            unsigned short* __restrict__ T) {
    int idx = blockIdx.x * blockDim.x + threadIdx.x;
    if (idx >= DRANGE) return;
    float d = (float)(idx - (N_ - 1));
    float h[NEDGE];
    #pragma unroll
    for (int o = 0; o < NEDGE; o++) h[o] = bias[o];
    float tscale = ts[0];
    for (int f = 0; f < NFREQ; f++) {
        float s, c;
        sincosf(d * (tfrq[f] * tscale), &s, &c);
        #pragma unroll
        for (int o = 0; o < NEDGE; o++)
            h[o] = fmaf(s, W[o * FANIN + f], fmaf(c, W[o * FANIN + NFREQ + f], h[o]));
    }
    uint4 r0, r1;
    r0.x = bf16rne(h[0])  | (bf16rne(h[1])  << 16);
    r0.y = bf16rne(h[2])  | (bf16rne(h[3])  << 16);
    r0.z = bf16rne(h[4])  | (bf16rne(h[5])  << 16);
    r0.w = bf16rne(h[6])  | (bf16rne(h[7])  << 16);
    r1.x = bf16rne(h[8])  | (bf16rne(h[9])  << 16);
    r1.y = bf16rne(h[10]) | (bf16rne(h[11]) << 16);
    r1.z = bf16rne(h[12]) | (bf16rne(h[13]) << 16);
    r1.w = bf16rne(h[14]) | (bf16rne(h[15]) << 16);
    uint4* Tp = (uint4*)(T + (size_t)idx * 16);
    Tp[0] = r0; Tp[1] = r1;
}

// ---------------- kernel 2: per-node frame (12 floats packed, 64B stride) ----------------
__global__ void compute_F(const float* __restrict__ X, float* __restrict__ F) {
    int idx = blockIdx.x * blockDim.x + threadIdx.x;
    if (idx >= B_ * N_) return;
    int n = idx & (N_ - 1);
    const float* Xp = X + (size_t)idx * 3;
    float o[12];
    o[0] = Xp[0]; o[1] = Xp[1]; o[2] = Xp[2];
    #pragma unroll
    for (int i = 3; i < 12; i++) o[i] = 0.0f;
    if (n != 0 && n < N_ - 2) {
        F3 xm = f3(Xp[-3], Xp[-2], Xp[-1]);
        F3 x0 = f3(Xp[0], Xp[1], Xp[2]);
        F3 xp = f3(Xp[3], Xp[4], Xp[5]);
        F3 u2 = norm3(sub3(x0, xm));
        F3 u1 = norm3(sub3(xp, x0));
        F3 n2 = norm3(cross3(u2, u1));
        F3 o1 = norm3(sub3(u2, u1));
        F3 cc = cross3(o1, n2);
        o[3] = o1.x; o[4] = o1.y; o[5] = o1.z;
        o[6] = n2.x; o[7] = n2.y; o[8] = n2.z;
        o[9] = cc.x; o[10] = cc.y; o[11] = cc.z;
    }
    float4* Fp = (float4*)(F + (size_t)idx * 16);
    Fp[0] = make_float4(o[0], o[1], o[2], o[3]);
    Fp[1] = make_float4(o[4], o[5], o[6], o[7]);
    Fp[2] = make_float4(o[8], o[9], o[10], o[11]);
}

// ---------------- core per-edge computation (ARITHMETIC UNCHANGED since R4) ----------------
__device__ inline void compute_edge(float4 a0, float4 a1, float4 a2,
                                    const float* __restrict__ F,
                                    const unsigned short* __restrict__ T,
                                    const float (*sWq)[8],
                                    size_t bbase, int n, int j,
                                    float* __restrict__ h) {
    const float4* fjp = (const float4*)(F + (bbase + (size_t)j) * 16);
    float4 b0 = fjp[0], b1 = fjp[1], b2 = fjp[2];
    const uint4* tp = (const uint4*)(T + (size_t)(j - n + (N_ - 1)) * 16);
    uint4 t0 = tp[0], t1 = tp[1];
    float tv[16];
    unpack8(t0, tv);
    unpack8(t1, tv + 8);

    float A1x = a0.w, A1y = a1.x, A1z = a1.y;
    float A2x = a1.z, A2y = a1.w, A2z = a2.x;
    float A3x = a2.y, A3y = a2.z, A3z = a2.w;
    float B1x = b0.w, B1y = b1.x, B1z = b1.y;
    float B2x = b1.z, B2y = b1.w, B2z = b2.x;
    float B3x = b2.y, B3y = b2.z, B3z = b2.w;

    float dX0 = b0.x - a0.x, dX1 = b0.y - a0.y, dX2 = b0.z - a0.z;
    float v0 = A1x*dX0 + A1y*dX1 + A1z*dX2;
    float v1 = A2x*dX0 + A2y*dX1 + A2z*dX2;
    float v2 = A3x*dX0 + A3y*dX1 + A3z*dX2;
    float vinv = 1.0f / fmaxf(sqrtf(v0*v0 + v1*v1 + v2*v2), EPSF);
    float dU0 = v0*vinv, dU1 = v1*vinv, dU2 = v2*vinv;

    float R00 = A1x*B1x + A2x*B2x + A3x*B3x;
    float R11 = A1y*B1y + A2y*B2y + A3y*B3y;
    float R22 = A1z*B1z + A2z*B2z + A3z*B3z;
    float R21 = A1z*B1y + A2z*B2y + A3z*B3y;
    float R12 = A1y*B1z + A2y*B2z + A3y*B3z;
    float R02 = A1x*B1z + A2x*B2z + A3x*B3z;
    float R20 = A1z*B1x + A2z*B2x + A3z*B3x;
    float R10 = A1y*B1x + A2y*B2x + A3y*B3x;
    float R01 = A1x*B1y + A2x*B2y + A3x*B3y;

    float mg0 = 0.5f * sqrtf(fabsf(1.0f + R00 - R11 - R22) + EPSF);
    float mg1 = 0.5f * sqrtf(fabsf(1.0f - R00 + R11 - R22) + EPSF);
    float mg2 = 0.5f * sqrtf(fabsf(1.0f - R00 - R11 + R22) + EPSF);
    float qx = signf0(R21 - R12) * mg0;
    float qy = signf0(R02 - R20) * mg1;
    float qz = signf0(R10 - R01) * mg2;
    float qw = 0.5f * sqrtf(fmaxf(1.0f + R00 + R11 + R22, 0.0f) + EPSF);
    float qinv = 1.0f / fmaxf(sqrtf(qx*qx + qy*qy + qz*qz + qw*qw), EPSF);
    qx *= qinv; qy *= qinv; qz *= qinv; qw *= qinv;

    float q[7] = {dU0, dU1, dU2, qx, qy, qz, qw};
    #pragma unroll
    for (int o = 0; o < NEDGE; o++) {
        float a = tv[o];
        #pragma unroll
        for (int f = 0; f < 7; f++) a = fmaf(q[f], sWq[o][f], a);
        h[o] = a;
    }
}

// ---------------- edge pass: 4 k x 256 n per block, LDS-staged, transposed stores ----------------
// grid = 8(b) x 12(kq) x 32(chunk) = 3072 blocks. b in low 3 bits (XCD pin).
__launch_bounds__(256)
__global__ void edge_pass(const int* __restrict__ E, const float* __restrict__ F,
                          const unsigned short* __restrict__ T, const float* __restrict__ Wfull,
                          float* __restrict__ acc, float* __restrict__ out) {
    int bid = blockIdx.x;
    int b = bid & 7;
    int r = bid >> 3;
    int kq = r % 12;            // 4-k group
    int chunk = r / 12;         // 0..31
    int tid = threadIdx.x;
    int n = chunk * 256 + tid;
    int lane = tid & 63, wid = tid >> 6;

    __shared__ float sF[256 * 17];          // staged F rows (pad 17 to dodge bank conflicts)
    __shared__ float sWq[NEDGE][8];
    __shared__ float sAcc[4][4][NEDGE];     // [wave][kk][channel]

    if (tid < NEDGE * 8) {
        int o = tid >> 3, f = tid & 7;
        sWq[o][f] = (f < 7) ? Wfull[o * FANIN + 16 + f] : 0.0f;
    }

    size_t bbase = (size_t)b * N_;

    // coop-stage this chunk's 256 F rows (64B each) coalesced: 4 float4/thread
    {
        const float4* Fg = (const float4*)(F + (bbase + (size_t)chunk * 256) * 16);
        #pragma unroll
        for (int s = 0; s < 4; s++) {
            int g = tid + 256 * s;
            float4 v = Fg[g];
            int rr = g >> 2, pp = g & 3;
            *(float4*)(sF + rr * 17 + pp * 4) = v;
        }
    }
    __syncthreads();
    float4 a0 = *(float4*)(sF + tid * 17 + 0);
    float4 a1 = *(float4*)(sF + tid * 17 + 4);
    float4 a2 = *(float4*)(sF + tid * 17 + 8);

    int4 js4 = *(const int4*)(E + (bbase + n) * K_ + kq * 4);
    int js[4] = {js4.x, js4.y, js4.z, js4.w};
    __syncthreads();   // sF now reusable as store-transpose buffer

    size_t outbase = (bbase + (size_t)chunk * 256) * (K_ * 16);  // floats

    #pragma unroll
    for (int kk = 0; kk < 4; kk++) {
        int k = kq * 4 + kk;
        float h[NEDGE];
        compute_edge(a0, a1, a2, F, T, sWq, bbase, n, js[kk], h);

        // stage h into LDS for transposed (coalesced) store
        #pragma unroll
        for (int qd = 0; qd < 4; qd++)
            *(float4*)(sF + tid * 17 + qd * 4) =
                make_float4(h[4*qd], h[4*qd+1], h[4*qd+2], h[4*qd+3]);

        // ssq butterfly over n (lane axis)
        #pragma unroll
        for (int o = 0; o < NEDGE; o++) {
            float v = h[o] * h[o];
            #pragma unroll
            for (int m = 1; m < 64; m <<= 1) v += __shfl_xor(v, m, 64);
            if (lane == 0) sAcc[wid][kk][o] = v;
        }
        __syncthreads();

        // coalesced store: 4 lanes cover one edge's 64B line (16 lines/instr)
        int p = tid & 3;
        #pragma unroll
        for (int s = 0; s < 4; s++) {
            int e = (tid >> 2) + 64 * s;
            float4 v = *(float4*)(sF + e * 17 + p * 4);
            *(float4*)(out + outbase + (size_t)e * (K_ * 16) + k * 16 + p * 4) = v;
        }
        __syncthreads();
    }

    // combine 4 waves x 4 kk x 16 channels, one atomic each
    if (tid < 64) {
        int kk = tid >> 4, o = tid & 15;
        float t = sAcc[0][kk][o] + sAcc[1][kk][o] + sAcc[2][kk][o] + sAcc[3][kk][o];
        atomicAdd(&acc[((size_t)b * K_ + kq * 4 + kk) * NEDGE + o], t);
    }
}

// ---------------- reciprocal norms ----------------
__global__ void inv_kernel(const float* __restrict__ acc, float* __restrict__ rinv) {
    int i = blockIdx.x * blockDim.x + threadIdx.x;
    if (i >= B_ * K_ * NEDGE) return;
    rinv[i] = 1.0f / fmaxf(sqrtf(acc[i]), EPSF);
}

// ---------------- rescale pass (streaming RMW, L3-resident re-read) ----------------
__launch_bounds__(256)
__global__ void scale_kernel(float* __restrict__ out, const float* __restrict__ rinv) {
    size_t idx = (size_t)blockIdx.x * blockDim.x + threadIdx.x;  // float4 index
    constexpr size_t TOTAL4 = (size_t)B_ * N_ * K_ * 4;
    if (idx >= TOTAL4) return;
    size_t e0 = idx * 4;
    unsigned int o0 = (unsigned int)(e0 & 15);
    unsigned int key = (unsigned int)(e0 >> 4);       // (b*N+n)*K + k
    unsigned int k = key % (unsigned int)K_;
    unsigned int b = key / (unsigned int)(N_ * K_);
    const float* rp = rinv + ((size_t)b * K_ + k) * 16 + o0;
    float4 vv = *reinterpret_cast<float4*>(out + e0);
    vv.x *= rp[0]; vv.y *= rp[1]; vv.z *= rp[2]; vv.w *= rp[3];
    *reinterpret_cast<float4*>(out + e0) = vv;
}

// ---------------- launch ----------------
extern "C" void kernel_launch(void* const* d_in, const int* in_sizes, int n_in,
                              void* d_out, int out_size, void* d_ws, size_t ws_size,
                              hipStream_t stream) {
    const float* X    = (const float*)d_in[0];   // p (B,N,3)
    const int*   E    = (const int*)d_in[1];     // e_idx (B,N,K)
    // d_in[2] = mask (unused by reference)
    const float* tfrq = (const float*)d_in[3];   // (8,)
    const float* ts   = (const float*)d_in[4];   // scalar
    const float* W    = (const float*)d_in[5];   // (16,23)
    const float* bias = (const float*)d_in[6];   // (16,)
    float* out = (float*)d_out;

    float* F = (float*)d_ws;                                          // 8*8192*16 f32 = 4.19 MB
    unsigned short* T = (unsigned short*)(F + (size_t)B_ * N_ * 16);  // 16383*16 bf16 = 524 KB
    float* acc  = (float*)(T + (size_t)DRANGE * 16);                  // 6144 f32
    float* rinv = acc + B_ * K_ * NEDGE;                              // 6144 f32

    hipMemsetAsync(acc, 0, (size_t)B_ * K_ * NEDGE * sizeof(float), stream);

    build_table<<<(DRANGE + 255) / 256, 256, 0, stream>>>(tfrq, ts, W, bias, T);
    compute_F<<<(B_ * N_ + 255) / 256, 256, 0, stream>>>(X, F);

    int grid = 8 * 12 * 32;   // 3072 blocks, b in low 3 bits
    edge_pass<<<grid, 256, 0, stream>>>(E, F, T, W, acc, out);

    inv_kernel<<<(B_ * K_ * NEDGE + 255) / 256, 256, 0, stream>>>(acc, rinv);

    constexpr size_t TOTAL4 = (size_t)B_ * N_ * K_ * 4;
    scale_kernel<<<(TOTAL4 + 255) / 256, 256, 0, stream>>>(out, rinv);
}

// Round 7
// 146.286 us; speedup vs baseline: 1.2990x; 1.2990x over previous
//
#include <hip/hip_runtime.h>
#include <math.h>

// Problem constants (from reference)
constexpr int B_ = 8;
constexpr int N_ = 8192;
constexpr int K_ = 48;
constexpr int NFREQ = 8;    // NUM_POS/2
constexpr int NEDGE = 16;
constexpr int FANIN = 23;   // NUM_POS + 7
constexpr float EPSF = 1e-12f;
constexpr int DRANGE = 2 * N_ - 1;  // 16383 possible d = j-n values, offset N_-1

// ---------------- helpers ----------------
struct F3 { float x, y, z; };
__device__ inline F3 f3(float a, float b, float c) { F3 r{a,b,c}; return r; }
__device__ inline F3 sub3(F3 a, F3 b) { return f3(a.x-b.x, a.y-b.y, a.z-b.z); }
__device__ inline F3 cross3(F3 a, F3 b) {
    return f3(a.y*b.z - a.z*b.y, a.z*b.x - a.x*b.z, a.x*b.y - a.y*b.x);
}
__device__ inline F3 norm3(F3 a) {
    float n = sqrtf(a.x*a.x + a.y*a.y + a.z*a.z);
    float inv = 1.0f / fmaxf(n, EPSF);
    return f3(a.x*inv, a.y*inv, a.z*inv);
}
__device__ inline float signf0(float x) {
    return (x > 0.0f) ? 1.0f : ((x < 0.0f) ? -1.0f : 0.0f);
}
__device__ inline unsigned int bf16rne(float x) {
    unsigned int u = __float_as_uint(x);
    return (u + 0x7fffu + ((u >> 16) & 1u)) >> 16;
}
// unpack 8 bf16 (one uint4) -> 8 floats
__device__ inline void unpack8(uint4 v, float* f) {
    f[0] = __uint_as_float(v.x << 16); f[1] = __uint_as_float(v.x & 0xffff0000u);
    f[2] = __uint_as_float(v.y << 16); f[3] = __uint_as_float(v.y & 0xffff0000u);
    f[4] = __uint_as_float(v.z << 16); f[5] = __uint_as_float(v.z & 0xffff0000u);
    f[6] = __uint_as_float(v.w << 16); f[7] = __uint_as_float(v.w & 0xffff0000u);
}

// ---------------- kernel 1: positional-encoding table (bf16, 32B rows) ----------------
__global__ void build_table(const float* __restrict__ tfrq, const float* __restrict__ ts,
                            const float* __restrict__ W, const float* __restrict__ bias,
                            unsigned short* __restrict__ T) {
    int idx = blockIdx.x * blockDim.x + threadIdx.x;
    if (idx >= DRANGE) return;
    float d = (float)(idx - (N_ - 1));
    float h[NEDGE];
    #pragma unroll
    for (int o = 0; o < NEDGE; o++) h[o] = bias[o];
    float tscale = ts[0];
    for (int f = 0; f < NFREQ; f++) {
        float s, c;
        sincosf(d * (tfrq[f] * tscale), &s, &c);
        #pragma unroll
        for (int o = 0; o < NEDGE; o++)
            h[o] = fmaf(s, W[o * FANIN + f], fmaf(c, W[o * FANIN + NFREQ + f], h[o]));
    }
    uint4 r0, r1;
    r0.x = bf16rne(h[0])  | (bf16rne(h[1])  << 16);
    r0.y = bf16rne(h[2])  | (bf16rne(h[3])  << 16);
    r0.z = bf16rne(h[4])  | (bf16rne(h[5])  << 16);
    r0.w = bf16rne(h[6])  | (bf16rne(h[7])  << 16);
    r1.x = bf16rne(h[8])  | (bf16rne(h[9])  << 16);
    r1.y = bf16rne(h[10]) | (bf16rne(h[11]) << 16);
    r1.z = bf16rne(h[12]) | (bf16rne(h[13]) << 16);
    r1.w = bf16rne(h[14]) | (bf16rne(h[15]) << 16);
    uint4* Tp = (uint4*)(T + (size_t)idx * 16);
    Tp[0] = r0; Tp[1] = r1;
}

// ---------------- kernel 2: per-node frame (12 floats packed, 64B stride) ----------------
__global__ void compute_F(const float* __restrict__ X, float* __restrict__ F) {
    int idx = blockIdx.x * blockDim.x + threadIdx.x;
    if (idx >= B_ * N_) return;
    int n = idx & (N_ - 1);
    const float* Xp = X + (size_t)idx * 3;
    float o[12];
    o[0] = Xp[0]; o[1] = Xp[1]; o[2] = Xp[2];
    #pragma unroll
    for (int i = 3; i < 12; i++) o[i] = 0.0f;
    if (n != 0 && n < N_ - 2) {
        F3 xm = f3(Xp[-3], Xp[-2], Xp[-1]);
        F3 x0 = f3(Xp[0], Xp[1], Xp[2]);
        F3 xp = f3(Xp[3], Xp[4], Xp[5]);
        F3 u2 = norm3(sub3(x0, xm));
        F3 u1 = norm3(sub3(xp, x0));
        F3 n2 = norm3(cross3(u2, u1));
        F3 o1 = norm3(sub3(u2, u1));
        F3 cc = cross3(o1, n2);
        o[3] = o1.x; o[4] = o1.y; o[5] = o1.z;
        o[6] = n2.x; o[7] = n2.y; o[8] = n2.z;
        o[9] = cc.x; o[10] = cc.y; o[11] = cc.z;
    }
    float4* Fp = (float4*)(F + (size_t)idx * 16);
    Fp[0] = make_float4(o[0], o[1], o[2], o[3]);
    Fp[1] = make_float4(o[4], o[5], o[6], o[7]);
    Fp[2] = make_float4(o[8], o[9], o[10], o[11]);
}

// ---------------- core per-edge computation (ARITHMETIC UNCHANGED since R4) ----------------
__device__ inline void compute_edge(float4 a0, float4 a1, float4 a2,
                                    const float* __restrict__ F,
                                    const unsigned short* __restrict__ T,
                                    const float (*sWq)[8],
                                    size_t bbase, int n, int j,
                                    float* __restrict__ h) {
    const float4* fjp = (const float4*)(F + (bbase + (size_t)j) * 16);
    float4 b0 = fjp[0], b1 = fjp[1], b2 = fjp[2];
    const uint4* tp = (const uint4*)(T + (size_t)(j - n + (N_ - 1)) * 16);
    uint4 t0 = tp[0], t1 = tp[1];
    float tv[16];
    unpack8(t0, tv);
    unpack8(t1, tv + 8);

    float A1x = a0.w, A1y = a1.x, A1z = a1.y;
    float A2x = a1.z, A2y = a1.w, A2z = a2.x;
    float A3x = a2.y, A3y = a2.z, A3z = a2.w;
    float B1x = b0.w, B1y = b1.x, B1z = b1.y;
    float B2x = b1.z, B2y = b1.w, B2z = b2.x;
    float B3x = b2.y, B3y = b2.z, B3z = b2.w;

    float dX0 = b0.x - a0.x, dX1 = b0.y - a0.y, dX2 = b0.z - a0.z;
    float v0 = A1x*dX0 + A1y*dX1 + A1z*dX2;
    float v1 = A2x*dX0 + A2y*dX1 + A2z*dX2;
    float v2 = A3x*dX0 + A3y*dX1 + A3z*dX2;
    float vinv = 1.0f / fmaxf(sqrtf(v0*v0 + v1*v1 + v2*v2), EPSF);
    float dU0 = v0*vinv, dU1 = v1*vinv, dU2 = v2*vinv;

    float R00 = A1x*B1x + A2x*B2x + A3x*B3x;
    float R11 = A1y*B1y + A2y*B2y + A3y*B3y;
    float R22 = A1z*B1z + A2z*B2z + A3z*B3z;
    float R21 = A1z*B1y + A2z*B2y + A3z*B3y;
    float R12 = A1y*B1z + A2y*B2z + A3y*B3z;
    float R02 = A1x*B1z + A2x*B2z + A3x*B3z;
    float R20 = A1z*B1x + A2z*B2x + A3z*B3x;
    float R10 = A1y*B1x + A2y*B2x + A3y*B3x;
    float R01 = A1x*B1y + A2x*B2y + A3x*B3y;

    float mg0 = 0.5f * sqrtf(fabsf(1.0f + R00 - R11 - R22) + EPSF);
    float mg1 = 0.5f * sqrtf(fabsf(1.0f - R00 + R11 - R22) + EPSF);
    float mg2 = 0.5f * sqrtf(fabsf(1.0f - R00 - R11 + R22) + EPSF);
    float qx = signf0(R21 - R12) * mg0;
    float qy = signf0(R02 - R20) * mg1;
    float qz = signf0(R10 - R01) * mg2;
    float qw = 0.5f * sqrtf(fmaxf(1.0f + R00 + R11 + R22, 0.0f) + EPSF);
    float qinv = 1.0f / fmaxf(sqrtf(qx*qx + qy*qy + qz*qz + qw*qw), EPSF);
    qx *= qinv; qy *= qinv; qz *= qinv; qw *= qinv;

    float q[7] = {dU0, dU1, dU2, qx, qy, qz, qw};
    #pragma unroll
    for (int o = 0; o < NEDGE; o++) {
        float a = tv[o];
        #pragma unroll
        for (int f = 0; f < 7; f++) a = fmaf(q[f], sWq[o][f], a);
        h[o] = a;
    }
}

// ---------------- edge pass: wave = 4n x 16k, contiguous 1KB stores ----------------
// grid = 8(b) x 3(kg) x 128(nt of 64 n) = 3072 blocks. b in low 3 bits (XCD pin).
// Each thread: 4 iterations (4 different n, same k). Wave-private LDS transpose
// (no block barrier) turns per-edge 64B lines into one contiguous 1KB store/instr.
__launch_bounds__(256)
__global__ void edge_pass(const int* __restrict__ E, const float* __restrict__ F,
                          const unsigned short* __restrict__ T, const float* __restrict__ Wfull,
                          float* __restrict__ acc, float* __restrict__ out) {
    int bid = blockIdx.x;
    int b = bid & 7;
    int r = bid >> 3;
    int kg = r % 3;             // k-group of 16
    int nt = r / 3;             // 0..127
    int tid = threadIdx.x;
    int w = tid >> 6, l = tid & 63;
    int nn = l >> 4, kk = l & 15;
    int k = kg * 16 + kk;

    __shared__ float sT[4][64 * 17];       // wave-private transpose buffers (pad 17)
    __shared__ float sWq[NEDGE][8];
    __shared__ float sAcc[4][16][NEDGE];

    if (tid < NEDGE * 8) {
        int o = tid >> 3, f = tid & 7;
        sWq[o][f] = (f < 7) ? Wfull[o * FANIN + 16 + f] : 0.0f;
    }
    __syncthreads();

    size_t bbase = (size_t)b * N_;
    int nbase = nt * 64;
    float* myT = sT[w];

    float vsq[NEDGE];
    #pragma unroll
    for (int o = 0; o < NEDGE; o++) vsq[o] = 0.0f;

    for (int it = 0; it < 4; it++) {
        int n = nbase + it * 16 + w * 4 + nn;
        size_t node = bbase + n;
        const float4* fnp = (const float4*)(F + node * 16);
        float4 a0 = fnp[0], a1 = fnp[1], a2 = fnp[2];
        int j = E[node * K_ + k];

        float h[NEDGE];
        compute_edge(a0, a1, a2, F, T, sWq, bbase, n, j, h);

        #pragma unroll
        for (int o = 0; o < NEDGE; o++) vsq[o] = fmaf(h[o], h[o], vsq[o]);

        // wave-private LDS transpose (lockstep wave -> no __syncthreads)
        #pragma unroll
        for (int q = 0; q < 4; q++)
            *(float4*)(myT + l * 17 + q * 4) =
                make_float4(h[4*q], h[4*q+1], h[4*q+2], h[4*q+3]);

        // store: instr s writes n-row s's 16 edges = contiguous 1KB, uniform base
        #pragma unroll
        for (int s = 0; s < 4; s++) {
            int n_s = nbase + it * 16 + w * 4 + s;
            float4 v = *(float4*)(myT + ((s << 4) + (l >> 2)) * 17 + (l & 3) * 4);
            size_t outb = ((bbase + n_s) * K_ + kg * 16) * 16;
            *(float4*)(out + outb + l * 4) = v;
        }
    }

    // ssq: reduce over the 4 n-subrows within the wave (lane bits 4-5)
    #pragma unroll
    for (int o = 0; o < NEDGE; o++) {
        float v = vsq[o];
        v += __shfl_xor(v, 16, 64);
        v += __shfl_xor(v, 32, 64);
        vsq[o] = v;
    }
    if (nn == 0 && l < 16) {
        #pragma unroll
        for (int o = 0; o < NEDGE; o++) sAcc[w][kk][o] = vsq[o];
    }
    __syncthreads();
    {
        int kk2 = tid >> 4, o = tid & 15;
        float t = sAcc[0][kk2][o] + sAcc[1][kk2][o] + sAcc[2][kk2][o] + sAcc[3][kk2][o];
        atomicAdd(&acc[((size_t)b * K_ + kg * 16 + kk2) * NEDGE + o], t);
    }
}

// ---------------- reciprocal norms ----------------
__global__ void inv_kernel(const float* __restrict__ acc, float* __restrict__ rinv) {
    int i = blockIdx.x * blockDim.x + threadIdx.x;
    if (i >= B_ * K_ * NEDGE) return;
    rinv[i] = 1.0f / fmaxf(sqrtf(acc[i]), EPSF);
}

// ---------------- rescale pass (streaming RMW, L3-resident re-read) ----------------
__launch_bounds__(256)
__global__ void scale_kernel(float* __restrict__ out, const float* __restrict__ rinv) {
    size_t idx = (size_t)blockIdx.x * blockDim.x + threadIdx.x;  // float4 index
    constexpr size_t TOTAL4 = (size_t)B_ * N_ * K_ * 4;
    if (idx >= TOTAL4) return;
    size_t e0 = idx * 4;
    unsigned int o0 = (unsigned int)(e0 & 15);
    unsigned int key = (unsigned int)(e0 >> 4);       // (b*N+n)*K + k
    unsigned int k = key % (unsigned int)K_;
    unsigned int b = key / (unsigned int)(N_ * K_);
    const float* rp = rinv + ((size_t)b * K_ + k) * 16 + o0;
    float4 vv = *reinterpret_cast<float4*>(out + e0);
    vv.x *= rp[0]; vv.y *= rp[1]; vv.z *= rp[2]; vv.w *= rp[3];
    *reinterpret_cast<float4*>(out + e0) = vv;
}

// ---------------- launch ----------------
extern "C" void kernel_launch(void* const* d_in, const int* in_sizes, int n_in,
                              void* d_out, int out_size, void* d_ws, size_t ws_size,
                              hipStream_t stream) {
    const float* X    = (const float*)d_in[0];   // p (B,N,3)
    const int*   E    = (const int*)d_in[1];     // e_idx (B,N,K)
    // d_in[2] = mask (unused by reference)
    const float* tfrq = (const float*)d_in[3];   // (8,)
    const float* ts   = (const float*)d_in[4];   // scalar
    const float* W    = (const float*)d_in[5];   // (16,23)
    const float* bias = (const float*)d_in[6];   // (16,)
    float* out = (float*)d_out;

    float* F = (float*)d_ws;                                          // 8*8192*16 f32 = 4.19 MB
    unsigned short* T = (unsigned short*)(F + (size_t)B_ * N_ * 16);  // 16383*16 bf16 = 524 KB
    float* acc  = (float*)(T + (size_t)DRANGE * 16);                  // 6144 f32
    float* rinv = acc + B_ * K_ * NEDGE;                              // 6144 f32

    hipMemsetAsync(acc, 0, (size_t)B_ * K_ * NEDGE * sizeof(float), stream);

    build_table<<<(DRANGE + 255) / 256, 256, 0, stream>>>(tfrq, ts, W, bias, T);
    compute_F<<<(B_ * N_ + 255) / 256, 256, 0, stream>>>(X, F);

    int grid = 8 * 3 * 128;   // 3072 blocks, b in low 3 bits
    edge_pass<<<grid, 256, 0, stream>>>(E, F, T, W, acc, out);

    inv_kernel<<<(B_ * K_ * NEDGE + 255) / 256, 256, 0, stream>>>(acc, rinv);

    constexpr size_t TOTAL4 = (size_t)B_ * N_ * K_ * 4;
    scale_kernel<<<(TOTAL4 + 255) / 256, 256, 0, stream>>>(out, rinv);
}